// Round 4
// baseline (731.554 us; speedup 1.0000x reference)
//
#include <hip/hip_runtime.h>

#define T_DIM 8
#define M_DIM 16384
#define K_DIM 128
#define N_DIM 1024

typedef __attribute__((ext_vector_type(8))) short bf16x8_t;
typedef __attribute__((ext_vector_type(4))) float f32x4_t;

__device__ __forceinline__ unsigned short f2bf(float f) {
  unsigned int v;
  __builtin_memcpy(&v, &f, 4);
  v += 0x7FFFu + ((v >> 16) & 1u);  // round-to-nearest-even
  return (unsigned short)(v >> 16);
}

// tanh-form gelu: g = x * t/(t+1), t = exp2(2*sqrt(2/pi)*log2(e)*(x+0.044715 x^3))
// max abs err vs exact erf-gelu ~3e-4. Clamp the nonlinear arg so t stays finite.
__device__ __forceinline__ float gelu_tanh(float x) {
  float xc = fminf(fmaxf(x, -8.f), 8.f);
  float y = 2.3022144f * __builtin_fmaf(0.044715f * xc * xc, xc, xc);
  float t = __builtin_amdgcn_exp2f(y);
  return x * t * __builtin_amdgcn_rcpf(t + 1.0f);
}

// W[t][k][n] fp32 -> WT[t][n][k] bf16, so the GEMM's B operand is k-contiguous.
__global__ __launch_bounds__(256) void transpose_w(
    const float* __restrict__ W, unsigned short* __restrict__ WT) {
  __shared__ __align__(16) unsigned short tile[64][72];
  int b = blockIdx.x;  // 8 t * 2 kt * 16 nt = 256 blocks
  int t = b >> 5;
  int r = b & 31;
  int kt = r >> 4;  // 0..1
  int nt = r & 15;  // 0..15
  int tid = threadIdx.x;
  const float* src =
      W + (size_t)t * (K_DIM * N_DIM) + (size_t)(kt * 64) * N_DIM + nt * 64;
#pragma unroll
  for (int it = 0; it < 4; ++it) {
    int li = it * 256 + tid;  // 0..1023
    int k = li >> 4;          // 0..63
    int c = li & 15;          // 0..15 (4-float chunks)
    float4 v = *(const float4*)(src + (size_t)k * N_DIM + c * 4);
    unsigned short u[4] = {f2bf(v.x), f2bf(v.y), f2bf(v.z), f2bf(v.w)};
    *(uint2*)&tile[k][c * 4] = *(const uint2*)u;  // 8 B, aligned (row stride 144 B)
  }
  __syncthreads();
  unsigned short* dst =
      WT + (size_t)t * (N_DIM * K_DIM) + (size_t)(nt * 64) * K_DIM + kt * 64;
#pragma unroll
  for (int it = 0; it < 2; ++it) {
    int li = it * 256 + tid;  // 0..511
    int n = li >> 3;          // 0..63
    int ck = li & 7;          // 0..7
    __align__(16) unsigned short tmp[8];
#pragma unroll
    for (int j = 0; j < 8; ++j) tmp[j] = tile[ck * 8 + j][n];
    *(uint4*)(dst + (size_t)n * K_DIM + ck * 8) = *(const uint4*)tmp;
  }
}

// R3 (re-run; prior attempt died to container infra, not kernel): per block =
// 16 rows x ALL 1024 cols -> the block's 64 KB fp32 output region is
// CONTIGUOUS in memory. Epilogue stages it in LDS and stores it as a
// byte-linear stream (addr = base + idx*16B), the same shape as the 6.25
// TB/s fillBuffer. Theory: R2's 512 B segments @ 4 KB stride were still
// channel-fragmenting HBM writes (~2.1 TB/s effective).
// 512 thr / 8 waves; wave wn owns n in [wn*128, wn*128+128) as 8 16x16 tiles.
// Single 16-row m-tile -> A fragments loaded from LDS ONCE, reused 8x.
// B (WT, bf16, k-contig) read per-fragment straight from L2 (256 KiB/t slice,
// resident; t-major dispatch keeps one slice hot per XCD).
// MFMA operands SWAPPED (bf first) -> D reg quad runs along n:
//   m = lane&15, n = ntile*16 + (lane>>4)*4 + rr   [m89/m91, operand-swapped]
__global__ __launch_bounds__(512, 4) void gemm_bias_gelu(
    const float* __restrict__ A,             // [T][M][K] fp32
    const unsigned short* __restrict__ WT,   // [T][N][K] bf16
    const float* __restrict__ bias,          // [T][N] fp32
    float* __restrict__ O) {                 // [T][M][N] fp32
  constexpr int LDT = 136;   // halves; 272 B row stride -> frag reads baseline
  constexpr int LDO = 1028;  // floats; +4 pad -> repack writes baseline,
                             // linear reads conflict-free
  __shared__ __align__(16) unsigned short sA[16 * LDT];  // 4352 B
  __shared__ __align__(16) float sO[16 * LDO];           // 65792 B
  // total 70144 B -> 2 blocks/CU (140.3 of 160 KB), 4 waves/SIMD

  int bid = blockIdx.x;  // 8192 = 8 t * 1024 mt, t-major
  int t = bid >> 10;
  int mt = bid & 1023;
  int tid = threadIdx.x;
  int lane = tid & 63;
  int wn = tid >> 6;   // 0..7: n-span owner
  int qk = lane >> 4;  // 0..3
  int lr = lane & 15;  // 0..15

  // ---- stage A once: 16 rows x 128 k fp32 -> bf16 LDS (1 float4/thread)
  const float* Ag =
      A + (size_t)t * ((size_t)M_DIM * K_DIM) + (size_t)(mt * 16) * K_DIM;
  {
    int row = tid >> 5;  // 0..15
    int c = tid & 31;    // 0..31 (4-float chunks)
    float4 va = *(const float4*)(Ag + (size_t)row * K_DIM + c * 4);
    unsigned short u[4] = {f2bf(va.x), f2bf(va.y), f2bf(va.z), f2bf(va.w)};
    *(uint2*)&sA[row * LDT + c * 4] = *(const uint2*)u;
  }
  __syncthreads();

  // ---- A fragments: load once, reuse across all 8 n-tiles
  bf16x8_t af[4];
#pragma unroll
  for (int kk = 0; kk < 4; ++kk)
    af[kk] = *(const bf16x8_t*)&sA[lr * LDT + kk * 32 + qk * 8];

  const unsigned short* Bg = WT + (size_t)t * (N_DIM * K_DIM);

  f32x4_t acc[8];
#pragma unroll
  for (int i = 0; i < 8; ++i) acc[i] = (f32x4_t){0.f, 0.f, 0.f, 0.f};

#pragma unroll
  for (int nt8 = 0; nt8 < 8; ++nt8) {
    const unsigned short* bp =
        Bg + (size_t)(wn * 128 + nt8 * 16 + lr) * K_DIM + qk * 8;
    bf16x8_t b0 = *(const bf16x8_t*)(bp);
    bf16x8_t b1 = *(const bf16x8_t*)(bp + 32);
    bf16x8_t b2 = *(const bf16x8_t*)(bp + 64);
    bf16x8_t b3 = *(const bf16x8_t*)(bp + 96);
    // swapped operands: D[r=n][c=m] = sum_k WT[n][k] * A[m][k]
    acc[nt8] = __builtin_amdgcn_mfma_f32_16x16x32_bf16(b0, af[0], acc[nt8], 0, 0, 0);
    acc[nt8] = __builtin_amdgcn_mfma_f32_16x16x32_bf16(b1, af[1], acc[nt8], 0, 0, 0);
    acc[nt8] = __builtin_amdgcn_mfma_f32_16x16x32_bf16(b2, af[2], acc[nt8], 0, 0, 0);
    acc[nt8] = __builtin_amdgcn_mfma_f32_16x16x32_bf16(b3, af[3], acc[nt8], 0, 0, 0);
  }

  // ---- epilogue: bias + gelu in regs -> LDS repack
  const float* bg = bias + t * N_DIM;
#pragma unroll
  for (int nt8 = 0; nt8 < 8; ++nt8) {
    int n0 = wn * 128 + nt8 * 16 + qk * 4;
    f32x4_t bv = *(const f32x4_t*)(bg + n0);
    f32x4_t o;
#pragma unroll
    for (int rr = 0; rr < 4; ++rr) o[rr] = gelu_tanh(acc[nt8][rr] + bv[rr]);
    *(f32x4_t*)&sO[lr * LDO + n0] = o;  // m = lr
  }
  __syncthreads();

  // ---- byte-linear store of the block's contiguous 64 KB output region.
  // N_DIM*4 = 4096 B = 256 chunks of 16 B, so addr = Og + idx*16 B exactly:
  // each wave-instr writes 1 KB dense, the block streams 64 KB sequential.
  float* Og = O + (size_t)t * ((size_t)M_DIM * N_DIM) +
              (size_t)(mt * 16) * N_DIM;
#pragma unroll
  for (int p = 0; p < 8; ++p) {
    int idx = p * 512 + tid;  // 0..4095
    int row = idx >> 8;       // 0..15
    int cc = idx & 255;       // f32x4 chunk within row
    f32x4_t v = *(const f32x4_t*)&sO[row * LDO + cc * 4];
    __builtin_nontemporal_store(
        v, (f32x4_t*)(Og + (size_t)row * N_DIM + cc * 4));
  }
}

extern "C" void kernel_launch(void* const* d_in, const int* in_sizes, int n_in,
                              void* d_out, int out_size, void* d_ws, size_t ws_size,
                              hipStream_t stream) {
  const float* A = (const float*)d_in[0];     // inputs  [8,1,16384,128] fp32
  const float* W = (const float*)d_in[1];     // weights [8,1,128,1024] fp32
  const float* bias = (const float*)d_in[2];  // biases  [8,1,1,1024] fp32
  float* O = (float*)d_out;                   // [8,1,16384,1024] fp32
  unsigned short* WT = (unsigned short*)d_ws; // 2 MiB scratch: W^T in bf16

  transpose_w<<<256, 256, 0, stream>>>(W, WT);
  gemm_bias_gelu<<<8192, 512, 0, stream>>>(A, WT, bias, O);
}

// Round 5
// 612.920 us; speedup vs baseline: 1.1936x; 1.1936x over previous
//
#include <hip/hip_runtime.h>

#define T_DIM 8
#define M_DIM 16384
#define K_DIM 128
#define N_DIM 1024

typedef __attribute__((ext_vector_type(8))) short bf16x8_t;
typedef __attribute__((ext_vector_type(4))) float f32x4_t;

__device__ __forceinline__ unsigned short f2bf(float f) {
  unsigned int v;
  __builtin_memcpy(&v, &f, 4);
  v += 0x7FFFu + ((v >> 16) & 1u);  // round-to-nearest-even
  return (unsigned short)(v >> 16);
}

// tanh-form gelu: g = x * t/(t+1), t = exp2(2*sqrt(2/pi)*log2(e)*(x+0.044715 x^3))
// max abs err vs exact erf-gelu ~3e-4. Clamp the nonlinear arg so t stays finite.
__device__ __forceinline__ float gelu_tanh(float x) {
  float xc = fminf(fmaxf(x, -8.f), 8.f);
  float y = 2.3022144f * __builtin_fmaf(0.044715f * xc * xc, xc, xc);
  float t = __builtin_amdgcn_exp2f(y);
  return x * t * __builtin_amdgcn_rcpf(t + 1.0f);
}

// W[t][k][n] fp32 -> WT[t][n][k] bf16, so the GEMM's B operand is k-contiguous.
__global__ __launch_bounds__(256) void transpose_w(
    const float* __restrict__ W, unsigned short* __restrict__ WT) {
  __shared__ __align__(16) unsigned short tile[64][72];
  int b = blockIdx.x;  // 8 t * 2 kt * 16 nt = 256 blocks
  int t = b >> 5;
  int r = b & 31;
  int kt = r >> 4;  // 0..1
  int nt = r & 15;  // 0..15
  int tid = threadIdx.x;
  const float* src =
      W + (size_t)t * (K_DIM * N_DIM) + (size_t)(kt * 64) * N_DIM + nt * 64;
#pragma unroll
  for (int it = 0; it < 4; ++it) {
    int li = it * 256 + tid;  // 0..1023
    int k = li >> 4;          // 0..63
    int c = li & 15;          // 0..15 (4-float chunks)
    float4 v = *(const float4*)(src + (size_t)k * N_DIM + c * 4);
    unsigned short u[4] = {f2bf(v.x), f2bf(v.y), f2bf(v.z), f2bf(v.w)};
    *(uint2*)&tile[k][c * 4] = *(const uint2*)u;  // 8 B, aligned (row stride 144 B)
  }
  __syncthreads();
  unsigned short* dst =
      WT + (size_t)t * (N_DIM * K_DIM) + (size_t)(nt * 64) * K_DIM + kt * 64;
#pragma unroll
  for (int it = 0; it < 2; ++it) {
    int li = it * 256 + tid;  // 0..511
    int n = li >> 3;          // 0..63
    int ck = li & 7;          // 0..7
    __align__(16) unsigned short tmp[8];
#pragma unroll
    for (int j = 0; j < 8; ++j) tmp[j] = tile[ck * 8 + j][n];
    *(uint4*)(dst + (size_t)n * K_DIM + ck * 8) = *(const uint4*)tmp;
  }
}

// R5: R2's validated decomposition (BM=64, t-major, LDS repack + linear-seg
// stores) with three structural tighteners:
//  1. A fragments live in REGISTERS (af[4][4], 64 VGPR, loaded once) -> sA is
//     dead after the prologue, so the output ping-pong buffer ALIASES it:
//     LDS 51.2 -> 34.8 KB -> 4 blocks/CU (16 waves/CU, was 12).
//  2. ONE barrier per 64-n chunk (was 2 per 128-n pass): ping-pong halves make
//     repack(c+1) and store(c) touch disjoint halves; the WAR on half c&1 is
//     covered transitively by barrier c+1. The compiler's vmcnt(0) drain at
//     each barrier now lands ~1 kcyc after the stores were issued (cheap).
//  3. Per-chunk live state is only bf[4]+acc[4] (32 VGPR) -> no R4-style
//     hoisting blowup; total ~120 VGPR fits the (256,4) cap.
// B stays n-split across waves (1x L2 traffic, R2's winning choice; R4's
// m-split 4x'd it). MFMA operands SWAPPED (bf first) -> D reg quad runs
// along n: m = lane&15, n = base + (lane>>4)*4 + rr  [m89/m91, swapped].
__global__ __launch_bounds__(256, 4) void gemm_bias_gelu(
    const float* __restrict__ A,             // [T][M][K] fp32
    const unsigned short* __restrict__ WT,   // [T][N][K] bf16
    const float* __restrict__ bias,          // [T][N] fp32
    float* __restrict__ O) {                 // [T][M][N] fp32
  constexpr int LDT = 136;  // halves per sA row (272 B)
  constexpr int LDO = 68;   // floats per sO row (272 B; stride 4 banks ->
                            // repack writes & store reads at b128 baseline)
  // Union LDS: prologue sA = 64*136*2 = 17408 B; main loop sO ping-pong =
  // 2 halves * 64 rows * 68 floats * 4 B = 2*17408 B. Total 34816 B.
  __shared__ __align__(16) unsigned char smem[2 * 64 * LDO * 4];
  unsigned short* sA = (unsigned short*)smem;

  int bid = blockIdx.x;  // 2048 = 8 t * 256 mt, t-major (WT slice hot per XCD)
  int t = bid >> 8;
  int mt = bid & 255;
  int tid = threadIdx.x;
  int lane = tid & 63;
  int wn = tid >> 6;   // wave owns 16 of each chunk's 64 n-cols
  int qk = lane >> 4;  // 0..3
  int lr = lane & 15;  // 0..15

  // ---- prologue: stage A (64 rows x 128 k fp32 -> bf16), then frags to regs
  const float* Ag =
      A + (size_t)t * ((size_t)M_DIM * K_DIM) + (size_t)(mt * 64) * K_DIM;
#pragma unroll
  for (int it = 0; it < 8; ++it) {
    int li = it * 256 + tid;  // 0..2047
    int row = li >> 5;        // 0..63
    int c = li & 31;          // 0..31 (4-float chunks)
    float4 va = *(const float4*)(Ag + (size_t)row * K_DIM + c * 4);
    unsigned short u[4] = {f2bf(va.x), f2bf(va.y), f2bf(va.z), f2bf(va.w)};
    *(uint2*)&sA[row * LDT + c * 4] = *(const uint2*)u;
  }
  __syncthreads();

  bf16x8_t af[4][4];  // [m-tile][kk] -- 64 VGPR, reused by all 16 chunks
#pragma unroll
  for (int i = 0; i < 4; ++i)
#pragma unroll
    for (int kk = 0; kk < 4; ++kk)
      af[i][kk] = *(const bf16x8_t*)&sA[(i * 16 + lr) * LDT + kk * 32 + qk * 8];
  __syncthreads();  // every wave's af reads done before chunk 0 repack
                    // overwrites the aliased smem

  const unsigned short* Bg = WT + (size_t)t * (N_DIM * K_DIM);
  const float* bg = bias + t * N_DIM;
  float* Og = O + (size_t)t * ((size_t)M_DIM * N_DIM) +
              (size_t)(mt * 64) * N_DIM;

#pragma unroll 1
  for (int c = 0; c < 16; ++c) {  // 16 chunks of 64 n
    // B frags for this wave's 16 n-rows of WT, straight from L2
    const unsigned short* bp =
        Bg + (size_t)(c * 64 + wn * 16 + lr) * K_DIM + qk * 8;
    bf16x8_t bf0 = *(const bf16x8_t*)(bp);
    bf16x8_t bf1 = *(const bf16x8_t*)(bp + 32);
    bf16x8_t bf2 = *(const bf16x8_t*)(bp + 64);
    bf16x8_t bf3 = *(const bf16x8_t*)(bp + 96);

    f32x4_t acc[4];
#pragma unroll
    for (int i = 0; i < 4; ++i) acc[i] = (f32x4_t){0.f, 0.f, 0.f, 0.f};
#pragma unroll
    for (int i = 0; i < 4; ++i) {  // 4 independent chains of 4 dependent MFMAs
      acc[i] = __builtin_amdgcn_mfma_f32_16x16x32_bf16(bf0, af[i][0], acc[i], 0, 0, 0);
      acc[i] = __builtin_amdgcn_mfma_f32_16x16x32_bf16(bf1, af[i][1], acc[i], 0, 0, 0);
      acc[i] = __builtin_amdgcn_mfma_f32_16x16x32_bf16(bf2, af[i][2], acc[i], 0, 0, 0);
      acc[i] = __builtin_amdgcn_mfma_f32_16x16x32_bf16(bf3, af[i][3], acc[i], 0, 0, 0);
    }

    // ---- bias + gelu in regs -> repack into ping-pong half
    float* sO = (float*)(smem + (c & 1) * (64 * LDO * 4));
    f32x4_t bv = *(const f32x4_t*)(bg + c * 64 + wn * 16 + qk * 4);
#pragma unroll
    for (int i = 0; i < 4; ++i) {
      f32x4_t o;
#pragma unroll
      for (int rr = 0; rr < 4; ++rr) o[rr] = gelu_tanh(acc[i][rr] + bv[rr]);
      // m = i*16 + lr, local n = wn*16 + qk*4
      *(f32x4_t*)&sO[(i * 16 + lr) * LDO + wn * 16 + qk * 4] = o;
    }
    __syncthreads();  // the only barrier per chunk

    // ---- linear-seg stores: per instr 4 rows x 256 B dense (2 full lines);
    // issued just before the next chunk's independent loads+MFMAs.
#pragma unroll
    for (int p = 0; p < 4; ++p) {
      int idx = p * 256 + tid;  // 0..1023
      int row = idx >> 4;       // 0..63
      int cc = idx & 15;        // f32x4 chunk within the 64-col chunk
      f32x4_t v = *(const f32x4_t*)&sO[row * LDO + cc * 4];
      __builtin_nontemporal_store(
          v, (f32x4_t*)(Og + (size_t)row * N_DIM + c * 64 + cc * 4));
    }
  }
}

extern "C" void kernel_launch(void* const* d_in, const int* in_sizes, int n_in,
                              void* d_out, int out_size, void* d_ws, size_t ws_size,
                              hipStream_t stream) {
  const float* A = (const float*)d_in[0];     // inputs  [8,1,16384,128] fp32
  const float* W = (const float*)d_in[1];     // weights [8,1,128,1024] fp32
  const float* bias = (const float*)d_in[2];  // biases  [8,1,1,1024] fp32
  float* O = (float*)d_out;                   // [8,1,16384,1024] fp32
  unsigned short* WT = (unsigned short*)d_ws; // 2 MiB scratch: W^T in bf16

  transpose_w<<<256, 256, 0, stream>>>(W, WT);
  gemm_bias_gelu<<<2048, 256, 0, stream>>>(A, WT, bias, O);
}